// Round 5
// baseline (111.170 us; speedup 1.0000x reference)
//
#include <hip/hip_runtime.h>
#include <cstdint>
#include <cstddef>

#define Bn 16
#define Hn 512
#define Wn 1024
#define NTOP 2048
#define KMAX 512
#define PAIRCAP 2048
#define SEGS 8
#define SEGCAP 2048
#define FBINS 4096
#define FBASE 126566      // (0x3DCCCCCD>>13); scores in (0.1,1) -> bins [0,3481]
#define KEYSN 4096
#define LISTCAP 256       // per-tile candidate cap (~21 expected; 12-sigma safe)
#define CPAD 32           // counter padding: 128B apart

// ---------------- Kernel 1: local-max detect + segmented append + fused histogram ----
// Tile 64x16, LDS tile 22x72 (x-aligned for float4). img = gray*mask.
// valid = (img==pool7x7(img)) && img>0.1 (mask>0 implied). LDS trimmed to ~13KB so
// 8 blocks/CU fit (round-4 regression: 19.4KB -> 4 blocks -> 50% occupancy).
__global__ __launch_bounds__(256) void detect_kernel(const float* __restrict__ gray,
                                                     const float* __restrict__ mask,
                                                     uint64_t* __restrict__ cand,
                                                     int* __restrict__ counts,
                                                     int* __restrict__ hist_g) {
    __shared__ float s_img[22][72];       // 6336 B; col c <-> gx = x0 + c - 4
    __shared__ float s_cmax[16][72];      // 4608 B
    __shared__ uint64_t s_list[LISTCAP];  // 2048 B
    __shared__ int s_n, s_base;

    const int x0 = blockIdx.x * 64;
    const int y0 = blockIdx.y * 16;
    const int b  = blockIdx.z;
    const int t  = threadIdx.x;
    const float* gb = gray + (size_t)b * Hn * Wn;
    const float* mb = mask + (size_t)b * Hn * Wn;

    if (t == 0) s_n = 0;

    const bool xedge = (blockIdx.x == 0) || (blockIdx.x == (Wn / 64 - 1));
    if (!xedge) {
        for (int l = t; l < 22 * 18; l += 256) {
            int r = l / 18, c4 = l % 18;
            int gy = y0 + r - 3;
            float4 v;
            if (gy >= 0 && gy < Hn) {
                const float4* gp = (const float4*)(gb + (size_t)gy * Wn + x0 - 4);
                const float4* mp = (const float4*)(mb + (size_t)gy * Wn + x0 - 4);
                float4 g = gp[c4], m = mp[c4];
                v = make_float4(g.x * m.x, g.y * m.y, g.z * m.z, g.w * m.w);
            } else {
                float ni = -__builtin_inff();
                v = make_float4(ni, ni, ni, ni);
            }
            *(float4*)&s_img[r][c4 * 4] = v;
        }
    } else {
        for (int l = t; l < 22 * 72; l += 256) {
            int r = l / 72, c = l % 72;
            int gy = y0 + r - 3, gx = x0 + c - 4;
            float v = -__builtin_inff();
            if (gy >= 0 && gy < Hn && gx >= 0 && gx < Wn) {
                int o = gy * Wn + gx;
                v = gb[o] * mb[o];
            }
            s_img[r][c] = v;
        }
    }
    __syncthreads();

    // vertical max over 7
    for (int l = t; l < 16 * 72; l += 256) {
        int r = l / 72, c = l % 72;
        float m = s_img[r][c];
#pragma unroll
        for (int d = 1; d < 7; ++d) m = fmaxf(m, s_img[r + d][c]);
        s_cmax[r][c] = m;
    }
    __syncthreads();

    // horizontal max over 7 + validity + LDS append (pixel c at col c+4)
    for (int l = t; l < 16 * 64; l += 256) {
        int r = l >> 6, c = l & 63;
        float p = s_cmax[r][c + 1];
#pragma unroll
        for (int d = 2; d < 8; ++d) p = fmaxf(p, s_cmax[r][c + d]);
        float v = s_img[r + 3][c + 4];
        if (v == p && v > 0.1f) {
            uint32_t idx = (uint32_t)((y0 + r) * Wn + (x0 + c));
            uint64_t key = ((uint64_t)__float_as_uint(v) << 32) | (uint32_t)(~idx);
            int pos = atomicAdd(&s_n, 1);
            if (pos < LISTCAP) s_list[pos] = key;
        }
    }
    __syncthreads();

    int m = s_n; if (m > LISTCAP) m = LISTCAP;
    const int seg = (blockIdx.y * gridDim.x + blockIdx.x) & (SEGS - 1);
    if (t == 0) s_base = atomicAdd(&counts[(b * SEGS + seg) * CPAD], m);
    __syncthreads();
    int base = s_base;
    uint64_t* dst = cand + ((size_t)b * SEGS + seg) * SEGCAP;
    for (int i = t; i < m; i += 256) {
        int d = base + i;
        if (d < SEGCAP) {
            uint64_t k = s_list[i];
            dst[d] = k;
            uint32_t sbits = (uint32_t)(k >> 32);
            int bin = (int)(sbits >> 13) - FBASE;
            bin = bin < 0 ? 0 : (bin > FBINS - 1 ? FBINS - 1 : bin);
            atomicAdd(&hist_g[(size_t)b * FBINS + bin], 1);
        }
    }
}

// ---------------- Kernel 2a: per-batch suffix scan of histogram -> T, cnt, cursors ---
// 16 blocks x 1024. Reads hist (int4/thread), shfl-hierarchical suffix scan, writes
// per-bin suffix sums (sfx_g), scatter cursor starts (in place over hist_g), and the
// threshold bin T + selected count to Tg.
__global__ __launch_bounds__(1024) void scan_kernel(int* __restrict__ hist_g,
                                                    int* __restrict__ sfx_g,
                                                    int* __restrict__ Tg) {
    __shared__ int scanA[64];
    const int b = blockIdx.x;
    const int t = threadIdx.x;
    const int lane = t & 63;
    const int w = t >> 6;
    const int base4 = t << 2;

    const int4 h4 = *(const int4*)(hist_g + (size_t)b * FBINS + base4);

    int loc = h4.x + h4.y + h4.z + h4.w;
    int x = loc;
#pragma unroll
    for (int d = 1; d < 64; d <<= 1) {
        int y = __shfl_down(x, d, 64);
        if (lane + d < 64) x += y;
    }
    if (lane == 0) scanA[w] = x;
    __syncthreads();
    if (w == 0) {
        int v = (lane < 16) ? scanA[lane] : 0;
#pragma unroll
        for (int d = 1; d < 16; d <<= 1) {
            int y = __shfl_down(v, d, 64);
            if (lane + d < 64) v += y;
        }
        if (lane < 16) scanA[lane] = v;
    }
    __syncthreads();
    const int total = scanA[0];
    const int target = total < NTOP ? total : NTOP;
    const int S_incl = x + ((w < 15) ? scanA[w + 1] : 0);

    int r = S_incl - loc;            // sfx[base4+4]
    int s3 = r + h4.w;
    int s2 = s3 + h4.z;
    int s1 = s2 + h4.y;
    int s0 = s1 + h4.x;
    *(int4*)(sfx_g  + (size_t)b * FBINS + base4) = make_int4(s0, s1, s2, s3);
    *(int4*)(hist_g + (size_t)b * FBINS + base4) = make_int4(s1, s2, s3, r);  // cursors

    // T = unique crossing bin; its sfx = selected count
    if (s0 >= target && s1 < target) { Tg[b * CPAD] = base4;     Tg[b * CPAD + 1] = s0 < KEYSN ? s0 : KEYSN; }
    if (s1 >= target && s2 < target) { Tg[b * CPAD] = base4 + 1; Tg[b * CPAD + 1] = s1 < KEYSN ? s1 : KEYSN; }
    if (s2 >= target && s3 < target) { Tg[b * CPAD] = base4 + 2; Tg[b * CPAD + 1] = s2 < KEYSN ? s2 : KEYSN; }
    if (s3 >= target && (base4 + 3 == FBINS - 1 || r < target)) { Tg[b * CPAD] = base4 + 3; Tg[b * CPAD + 1] = s3 < KEYSN ? s3 : KEYSN; }
}

// ---------------- Kernel 2b: parallel scatter to sorted-by-bin global slots ---------
// 128 blocks (batch x segment) x 256. Reads its segment coalesced, bins >= T scatter
// via global atomic cursors into keys_g[b][slot].
__global__ __launch_bounds__(256) void scatter_kernel(const uint64_t* __restrict__ cand,
                                                      const int* __restrict__ counts,
                                                      const int* __restrict__ Tg,
                                                      int* __restrict__ curs_g,
                                                      uint64_t* __restrict__ keys_g) {
    const int b = blockIdx.x >> 3;
    const int s = blockIdx.x & (SEGS - 1);
    const int t = threadIdx.x;
    int n = counts[(b * SEGS + s) * CPAD];
    if (n > SEGCAP) n = SEGCAP;
    const int T = Tg[b * CPAD];
    const uint64_t* src = cand + ((size_t)b * SEGS + s) * SEGCAP;
    uint64_t* kg = keys_g + (size_t)b * KEYSN;
    int* cg = curs_g + (size_t)b * FBINS;

    for (int i = t; i < n; i += 256) {
        uint64_t k = src[i];
        uint32_t sbits = (uint32_t)(k >> 32);
        int bin = (int)(sbits >> 13) - FBASE;
        bin = bin < 0 ? 0 : (bin > FBINS - 1 ? FBINS - 1 : bin);
        if (bin >= T) {
            int pos = atomicAdd(&cg[bin], 1);
            if (pos < KEYSN) kg[pos] = k;
        }
    }
}

// ---------------- Kernel 2c: per-bin sort + tie-run NMS + compact + output ----------
// 16 blocks x 1024. Small contiguous working set (keys_g[b][0..cnt)).
__global__ __launch_bounds__(1024) void sort_nms_kernel(const uint64_t* __restrict__ keys_g,
                                                        const int* __restrict__ sfx_g,
                                                        const int* __restrict__ Tg,
                                                        float* __restrict__ kp_out,
                                                        float* __restrict__ sc_out) {
    __shared__ uint64_t keys[KEYSN];     // 32 KB
    __shared__ int      sfx[FBINS];      // 16 KB
    __shared__ int      scanA[64];
    __shared__ uint32_t pairs[PAIRCAP];  // 8 KB
    __shared__ uint8_t  keep[NTOP];
    __shared__ int      sel[KMAX];
    __shared__ int      misc[4];

    const int b = blockIdx.x;
    const int t = threadIdx.x;
    const int lane = t & 63;
    const int w = t >> 6;
    const int T   = Tg[b * CPAD];
    const int cnt = Tg[b * CPAD + 1];

    *(int4*)&sfx[t << 2] = *(const int4*)(sfx_g + (size_t)b * FBINS + (t << 2));
    for (int i = t; i < KEYSN; i += 1024)
        keys[i] = (i < cnt) ? keys_g[(size_t)b * KEYSN + i] : 0ull;
    if (t < 4) misc[t] = 0;
    if (t < KMAX) sel[t] = -1;
    __syncthreads();

    // per-bin insertion sorts (descending by key: score desc, index asc)
    for (int j = t; j < FBINS; j += 1024) {
        if (j >= T) {
            int a0 = (j + 1 < FBINS) ? sfx[j + 1] : 0;
            int e0 = sfx[j];
            if (a0 > KEYSN) a0 = KEYSN;
            if (e0 > KEYSN) e0 = KEYSN;
            for (int a = a0 + 1; a < e0; ++a) {
                uint64_t v = keys[a]; int q = a - 1;
                while (q >= a0 && keys[q] < v) { keys[q + 1] = keys[q]; --q; }
                keys[q + 1] = v;
            }
        }
    }
    __syncthreads();

    // keep init + conflict pairs (only within equal-score runs: two valid candidates
    // with dist<3 lie in each other's 7x7 window => equal pooled max => tied)
    for (int j = t; j < NTOP; j += 1024) {
        uint32_t s = (uint32_t)(keys[j] >> 32);
        keep[j] = (s != 0u) ? 1 : 0;
        if (s) {
            uint32_t idx = ~(uint32_t)keys[j];
            int xq = (int)(idx & (Wn - 1)), yq = (int)(idx >> 10);
            for (int i = j - 1; i >= 0 && (uint32_t)(keys[i] >> 32) == s; --i) {
                uint32_t idx2 = ~(uint32_t)keys[i];
                int dx = xq - (int)(idx2 & (Wn - 1));
                int dy = yq - (int)(idx2 >> 10);
                if (dx * dx + dy * dy < 9) {
                    int p = atomicAdd(&misc[1], 1);
                    if (p < PAIRCAP) pairs[p] = ((uint32_t)j << 16) | (uint32_t)i;
                }
            }
        }
    }
    __syncthreads();

    if (t == 0) {   // sequential greedy resolve (tiny; canonical order via sort)
        int pc = misc[1]; if (pc > PAIRCAP) pc = PAIRCAP;
        for (int a = 1; a < pc; ++a) {
            uint32_t v = pairs[a]; int q = a - 1;
            while (q >= 0 && pairs[q] > v) { pairs[q + 1] = pairs[q]; --q; }
            pairs[q + 1] = v;
        }
        for (int a = 0; a < pc; ++a) {
            int j = (int)(pairs[a] >> 16), i = (int)(pairs[a] & 0xFFFF);
            if (keep[i]) keep[j] = 0;
        }
    }
    __syncthreads();

    // compaction prefix scan (shfl hierarchy), select first 512 kept
    int j0 = 2 * t, j1 = j0 + 1;
    int k0 = keep[j0], k1 = keep[j1];
    int sum = k0 + k1;
    int xp = sum;
#pragma unroll
    for (int d = 1; d < 64; d <<= 1) {
        int y = __shfl_up(xp, d, 64);
        if (lane >= d) xp += y;
    }
    if (lane == 63) scanA[w] = xp;
    __syncthreads();
    if (w == 0) {
        int v = (lane < 16) ? scanA[lane] : 0;
#pragma unroll
        for (int d = 1; d < 16; d <<= 1) {
            int y = __shfl_up(v, d, 64);
            if (lane >= d) v += y;
        }
        if (lane < 16) scanA[lane] = v;
    }
    __syncthreads();
    int pre = xp + ((w > 0) ? scanA[w - 1] : 0);
    int ex = pre - sum;
    if (k0 && ex < KMAX) sel[ex] = j0;
    if (k1 && (ex + k0) < KMAX) sel[ex + k0] = j1;
    __syncthreads();

    if (t < KMAX) {
        int jj = sel[t];
        float xo = 0.f, yo = 0.f, so = 0.f;
        if (jj >= 0) {
            uint32_t idx = ~(uint32_t)keys[jj];
            xo = (float)(idx & (Wn - 1));
            yo = (float)(idx >> 10);
            so = __uint_as_float((uint32_t)(keys[jj] >> 32));
        }
        kp_out[(size_t)b * KMAX * 2 + 2 * t]     = xo;
        kp_out[(size_t)b * KMAX * 2 + 2 * t + 1] = yo;
        sc_out[(size_t)b * KMAX + t]             = so;
    }
}

extern "C" void kernel_launch(void* const* d_in, const int* in_sizes, int n_in,
                              void* d_out, int out_size, void* d_ws, size_t ws_size,
                              hipStream_t stream) {
    const float* gray = (const float*)d_in[0];
    const float* mask = (const float*)d_in[1];
    float* out = (float*)d_out;
    float* kp_out = out;                        // 16*512*2
    float* sc_out = out + (size_t)Bn * KMAX * 2;

    // workspace layout (bytes)
    int*      counts = (int*)d_ws;                                  // 16384
    int*      Tg     = (int*)((char*)d_ws + 16384);                 // 2048
    int*      hist_g = (int*)((char*)d_ws + 18432);                 // 262144 (-> cursors)
    int*      sfx_g  = (int*)((char*)d_ws + 280576);                // 262144
    uint64_t* keys_g = (uint64_t*)((char*)d_ws + 542720);           // 524288
    uint64_t* cand   = (uint64_t*)((char*)d_ws + 1067008);          // 2097152

    hipMemsetAsync(d_ws, 0, 280576, stream);    // counts + Tg + hist

    dim3 g1(Wn / 64, Hn / 16, Bn);              // (16, 32, 16)
    detect_kernel<<<g1, 256, 0, stream>>>(gray, mask, cand, counts, hist_g);
    scan_kernel<<<Bn, 1024, 0, stream>>>(hist_g, sfx_g, Tg);
    scatter_kernel<<<Bn * SEGS, 256, 0, stream>>>(cand, counts, Tg, hist_g, keys_g);
    sort_nms_kernel<<<Bn, 1024, 0, stream>>>(keys_g, sfx_g, Tg, kp_out, sc_out);
}

// Round 6
// 86.588 us; speedup vs baseline: 1.2839x; 1.2839x over previous
//
#include <hip/hip_runtime.h>
#include <cstdint>
#include <cstddef>

#define Bn 16
#define Hn 512
#define Wn 1024
#define NTOP 2048
#define KMAX 512
#define PAIRCAP 2048
#define FBINS 4096
#define FBASE 126566      // (0x3DCCCCCD>>13); scores in (0.1,1) -> bins [0,3481]
#define KEYSN 4096
#define TILES 256         // tiles per batch: 16x16 grid of 64x32 tiles
#define SLOTS 96          // per-tile slot region (mean ~42 cand/tile; sub-Poisson)
#define LISTCAP 128

// ---------------- Kernel 1: local-max detect -> fixed per-tile slots ----------------
// Tile 64x32, LDS tile 38x72 (x-aligned for float4; col c <-> gx = x0+c-4).
// img = gray*mask. valid = (img==pool7x7(img)) && img>0.1 (mask>0 implied).
// ZERO global atomics: candidates go to this tile's fixed slot region; count is a
// plain store. Garbage slots beyond count are masked by the consumer.
__global__ __launch_bounds__(256) void detect_kernel(const float* __restrict__ gray,
                                                     const float* __restrict__ mask,
                                                     uint64_t* __restrict__ slots,
                                                     int* __restrict__ counts) {
    __shared__ float s_img[38][72];       // 10944 B
    __shared__ float s_cmax[32][72];      //  9216 B
    __shared__ uint64_t s_list[LISTCAP];  //  1024 B
    __shared__ int s_n;

    const int x0 = blockIdx.x * 64;
    const int y0 = blockIdx.y * 32;
    const int b  = blockIdx.z;
    const int t  = threadIdx.x;
    const float* gb = gray + (size_t)b * Hn * Wn;
    const float* mb = mask + (size_t)b * Hn * Wn;

    if (t == 0) s_n = 0;

    const bool xedge = (blockIdx.x == 0) || (blockIdx.x == gridDim.x - 1);
    if (!xedge) {
        for (int l = t; l < 38 * 18; l += 256) {
            int r = l / 18, c4 = l % 18;
            int gy = y0 + r - 3;
            float4 v;
            if (gy >= 0 && gy < Hn) {
                const float4* gp = (const float4*)(gb + (size_t)gy * Wn + x0 - 4);
                const float4* mp = (const float4*)(mb + (size_t)gy * Wn + x0 - 4);
                float4 g = gp[c4], m = mp[c4];
                v = make_float4(g.x * m.x, g.y * m.y, g.z * m.z, g.w * m.w);
            } else {
                float ni = -__builtin_inff();
                v = make_float4(ni, ni, ni, ni);
            }
            *(float4*)&s_img[r][c4 * 4] = v;
        }
    } else {
        for (int l = t; l < 38 * 72; l += 256) {
            int r = l / 72, c = l % 72;
            int gy = y0 + r - 3, gx = x0 + c - 4;
            float v = -__builtin_inff();
            if (gy >= 0 && gy < Hn && gx >= 0 && gx < Wn) {
                int o = gy * Wn + gx;
                v = gb[o] * mb[o];
            }
            s_img[r][c] = v;
        }
    }
    __syncthreads();

    // vertical max over 7
    for (int l = t; l < 32 * 72; l += 256) {
        int r = l / 72, c = l % 72;
        float m = s_img[r][c];
#pragma unroll
        for (int d = 1; d < 7; ++d) m = fmaxf(m, s_img[r + d][c]);
        s_cmax[r][c] = m;
    }
    __syncthreads();

    // horizontal max over 7 + validity + LDS append (pixel c at col c+4)
    for (int l = t; l < 32 * 64; l += 256) {
        int r = l >> 6, c = l & 63;
        float p = s_cmax[r][c + 1];
#pragma unroll
        for (int d = 2; d < 8; ++d) p = fmaxf(p, s_cmax[r][c + d]);
        float v = s_img[r + 3][c + 4];
        if (v == p && v > 0.1f) {
            uint32_t idx = (uint32_t)((y0 + r) * Wn + (x0 + c));
            uint64_t key = ((uint64_t)__float_as_uint(v) << 32) | (uint32_t)(~idx);
            int pos = atomicAdd(&s_n, 1);       // LDS atomic (cheap, on-CU)
            if (pos < LISTCAP) s_list[pos] = key;
        }
    }
    __syncthreads();

    int m = s_n; if (m > SLOTS) m = SLOTS;
    const int tile = blockIdx.y * gridDim.x + blockIdx.x;   // [0, 256)
    uint64_t* dst = slots + ((size_t)b * TILES + tile) * SLOTS;
    for (int i = t; i < m; i += 256) dst[i] = s_list[i];
    if (t == 0) counts[b * TILES + tile] = m;
}

// ---------------- Kernel 2: fused top-k + NMS, all-LDS, one block per batch --------
// Register-cache the batch's 24576 slot entries (24/thread). Phases: masked LDS-atomic
// histogram -> shfl-hierarchical suffix scan (T = threshold bin for top-2048) ->
// register-replay scatter into sorted-by-bin LDS slots -> per-bin insertion sorts ->
// tie-run NMS (conflicts require equal scores: two valid candidates with dist<3 lie in
// each other's 7x7 window) -> compact scan -> output. ZERO global atomics.
__global__ __launch_bounds__(1024) void topk_nms_kernel(const uint64_t* __restrict__ slots,
                                                        const int* __restrict__ counts,
                                                        float* __restrict__ kp_out,
                                                        float* __restrict__ sc_out) {
    __shared__ uint64_t keys[KEYSN];     // 32 KB
    __shared__ int      hist[FBINS];     // 16 KB (then scatter cursors)
    __shared__ int      sfx[FBINS];      // 16 KB
    __shared__ int      tcnt[TILES];     // 1 KB
    __shared__ int      scanA[64];
    __shared__ uint32_t pairs[PAIRCAP];  // 8 KB
    __shared__ uint8_t  keep[NTOP];      // 2 KB
    __shared__ int      sel[KMAX];       // 2 KB
    __shared__ int      misc[4];

    const int b = blockIdx.x;
    const int t = threadIdx.x;
    const int lane = t & 63;
    const int w = t >> 6;
    const uint64_t* sb = slots + (size_t)b * TILES * SLOTS;

    if (t < TILES) tcnt[t] = counts[b * TILES + t];
    *(int4*)&hist[t << 2] = make_int4(0, 0, 0, 0);
    if (t < 4) misc[t] = 0;
    if (t < KMAX) sel[t] = -1;
    __syncthreads();

    // Phase A: read all slot entries once (coalesced), keep in registers, LDS hist
    uint64_t ck[24];
    uint32_t vm = 0;
#pragma unroll
    for (int k = 0; k < 24; ++k) {
        int i = t + (k << 10);               // < 24576 = TILES*SLOTS
        int tile = i / SLOTS;
        int slot = i - tile * SLOTS;
        uint64_t key = sb[i];
        ck[k] = key;
        if (slot < tcnt[tile]) {
            vm |= (1u << k);
            uint32_t sbits = (uint32_t)(key >> 32);
            int bin = (int)(sbits >> 13) - FBASE;
            bin = bin < 0 ? 0 : (bin > FBINS - 1 ? FBINS - 1 : bin);
            atomicAdd(&hist[bin], 1);        // LDS atomic
        }
    }
    __syncthreads();

    // Phase B: hierarchical suffix scan over 4096 bins (thread t owns bins 4t..4t+3)
    const int base4 = t << 2;
    const int4 h4 = *(const int4*)&hist[base4];
    int loc = h4.x + h4.y + h4.z + h4.w;
    int x = loc;
#pragma unroll
    for (int d = 1; d < 64; d <<= 1) {
        int y = __shfl_down(x, d, 64);
        if (lane + d < 64) x += y;
    }
    if (lane == 0) scanA[w] = x;
    __syncthreads();
    if (w == 0) {
        int v = (lane < 16) ? scanA[lane] : 0;
#pragma unroll
        for (int d = 1; d < 16; d <<= 1) {
            int y = __shfl_down(v, d, 64);
            if (lane + d < 64) v += y;
        }
        if (lane < 16) scanA[lane] = v;
    }
    __syncthreads();
    const int total = scanA[0];
    const int target = total < NTOP ? total : NTOP;
    const int S_incl = x + ((w < 15) ? scanA[w + 1] : 0);

    int r = S_incl - loc;                    // sfx[base4+4]
    int s3 = r + h4.w;
    int s2 = s3 + h4.z;
    int s1 = s2 + h4.y;
    int s0 = s1 + h4.x;
    *(int4*)&sfx[base4]  = make_int4(s0, s1, s2, s3);
    *(int4*)&hist[base4] = make_int4(s1, s2, s3, r);    // cursors (own bins only)
    // threshold bin T: unique crossing sfx[T] >= target > sfx[T+1]
    if (s0 >= target && s1 < target) misc[2] = base4;
    if (s1 >= target && s2 < target) misc[2] = base4 + 1;
    if (s2 >= target && s3 < target) misc[2] = base4 + 2;
    if (s3 >= target && (base4 + 3 == FBINS - 1 || r < target)) misc[2] = base4 + 3;
    __syncthreads();
    const int T = misc[2];
    int cnt = sfx[T]; if (cnt > KEYSN) cnt = KEYSN;

    // Phase C: register-replay scatter into sorted-by-bin LDS slots
#pragma unroll
    for (int k = 0; k < 24; ++k) {
        if (vm & (1u << k)) {
            uint64_t key = ck[k];
            uint32_t sbits = (uint32_t)(key >> 32);
            int bin = (int)(sbits >> 13) - FBASE;
            bin = bin < 0 ? 0 : (bin > FBINS - 1 ? FBINS - 1 : bin);
            if (bin >= T) {
                int pos = atomicAdd(&hist[bin], 1);     // LDS atomic
                if (pos < KEYSN) keys[pos] = key;
            }
        }
    }
    for (int i = t; i < NTOP; i += 1024)     // [cnt,NTOP) disjoint from scatter [0,cnt)
        if (i >= cnt) keys[i] = 0ull;
    __syncthreads();

    // Phase D: per-bin insertion sorts (descending by key: score desc, index asc)
    for (int j = t; j < FBINS; j += 1024) {
        if (j >= T) {
            int a0 = (j + 1 < FBINS) ? sfx[j + 1] : 0;
            int e0 = sfx[j];
            if (a0 > KEYSN) a0 = KEYSN;
            if (e0 > KEYSN) e0 = KEYSN;
            for (int a = a0 + 1; a < e0; ++a) {
                uint64_t v = keys[a]; int q = a - 1;
                while (q >= a0 && keys[q] < v) { keys[q + 1] = keys[q]; --q; }
                keys[q + 1] = v;
            }
        }
    }
    __syncthreads();

    // Phase E: keep init + conflict pairs within equal-score runs only
    for (int j = t; j < NTOP; j += 1024) {
        uint32_t s = (uint32_t)(keys[j] >> 32);
        keep[j] = (s != 0u) ? 1 : 0;
        if (s) {
            uint32_t idx = ~(uint32_t)keys[j];
            int xq = (int)(idx & (Wn - 1)), yq = (int)(idx >> 10);
            for (int i = j - 1; i >= 0 && (uint32_t)(keys[i] >> 32) == s; --i) {
                uint32_t idx2 = ~(uint32_t)keys[i];
                int dx = xq - (int)(idx2 & (Wn - 1));
                int dy = yq - (int)(idx2 >> 10);
                if (dx * dx + dy * dy < 9) {        // dist < R=3, exact in integers
                    int p = atomicAdd(&misc[1], 1); // LDS atomic
                    if (p < PAIRCAP) pairs[p] = ((uint32_t)j << 16) | (uint32_t)i;
                }
            }
        }
    }
    __syncthreads();

    if (t == 0) {   // sequential greedy resolve (tiny; canonical order via sort)
        int pc = misc[1]; if (pc > PAIRCAP) pc = PAIRCAP;
        for (int a = 1; a < pc; ++a) {
            uint32_t v = pairs[a]; int q = a - 1;
            while (q >= 0 && pairs[q] > v) { pairs[q + 1] = pairs[q]; --q; }
            pairs[q + 1] = v;
        }
        for (int a = 0; a < pc; ++a) {
            int j = (int)(pairs[a] >> 16), i = (int)(pairs[a] & 0xFFFF);
            if (keep[i]) keep[j] = 0;
        }
    }
    __syncthreads();

    // Phase F: compaction prefix scan (shfl hierarchy), select first 512 kept
    int j0 = 2 * t, j1 = j0 + 1;
    int k0 = keep[j0], k1 = keep[j1];
    int sum = k0 + k1;
    int xp = sum;
#pragma unroll
    for (int d = 1; d < 64; d <<= 1) {
        int y = __shfl_up(xp, d, 64);
        if (lane >= d) xp += y;
    }
    if (lane == 63) scanA[w] = xp;
    __syncthreads();
    if (w == 0) {
        int v = (lane < 16) ? scanA[lane] : 0;
#pragma unroll
        for (int d = 1; d < 16; d <<= 1) {
            int y = __shfl_up(v, d, 64);
            if (lane >= d) v += y;
        }
        if (lane < 16) scanA[lane] = v;
    }
    __syncthreads();
    int pre = xp + ((w > 0) ? scanA[w - 1] : 0);
    int ex = pre - sum;
    if (k0 && ex < KMAX) sel[ex] = j0;
    if (k1 && (ex + k0) < KMAX) sel[ex + k0] = j1;
    __syncthreads();

    if (t < KMAX) {
        int jj = sel[t];
        float xo = 0.f, yo = 0.f, so = 0.f;
        if (jj >= 0) {
            uint32_t idx = ~(uint32_t)keys[jj];
            xo = (float)(idx & (Wn - 1));
            yo = (float)(idx >> 10);
            so = __uint_as_float((uint32_t)(keys[jj] >> 32));
        }
        kp_out[(size_t)b * KMAX * 2 + 2 * t]     = xo;
        kp_out[(size_t)b * KMAX * 2 + 2 * t + 1] = yo;
        sc_out[(size_t)b * KMAX + t]             = so;
    }
}

extern "C" void kernel_launch(void* const* d_in, const int* in_sizes, int n_in,
                              void* d_out, int out_size, void* d_ws, size_t ws_size,
                              hipStream_t stream) {
    const float* gray = (const float*)d_in[0];
    const float* mask = (const float*)d_in[1];
    float* out = (float*)d_out;
    float* kp_out = out;                        // 16*512*2
    float* sc_out = out + (size_t)Bn * KMAX * 2;

    // workspace: counts [16][256] int (16 KB), slots [16][256][96] u64 (3 MB).
    // No zero-init needed: counts/slots fully (re)written or masked each call.
    int*      counts = (int*)d_ws;
    uint64_t* slots  = (uint64_t*)((char*)d_ws + 16384);

    dim3 g1(Wn / 64, Hn / 32, Bn);              // (16, 16, 16) = 4096 blocks
    detect_kernel<<<g1, 256, 0, stream>>>(gray, mask, slots, counts);
    topk_nms_kernel<<<Bn, 1024, 0, stream>>>(slots, counts, kp_out, sc_out);
}

// Round 7
// 57.026 us; speedup vs baseline: 1.9495x; 1.5184x over previous
//
#include <hip/hip_runtime.h>
#include <cstdint>
#include <cstddef>

#define Bn 16
#define Hn 512
#define Wn 1024
#define NTOP 2048
#define KMAX 512
#define PAIRCAP 2048
#define FBINS 4096
#define FBASE 126566      // (0x3DCCCCCD>>13); scores in (0.1,1) -> bins [0,3481]
#define KEYSN 4096
#define TILES 256         // tiles per batch: 16x16 grid of 64x32 tiles
#define SLOTS 96          // per-tile slot region (mean ~42 cand/tile)
#define LISTCAP 128

// ---------------- Kernel 1: local-max detect -> fixed per-tile slots ----------------
// (unchanged from round 6 — ~27 us, zero global atomics)
__global__ __launch_bounds__(256) void detect_kernel(const float* __restrict__ gray,
                                                     const float* __restrict__ mask,
                                                     uint64_t* __restrict__ slots,
                                                     int* __restrict__ counts) {
    __shared__ float s_img[38][72];
    __shared__ float s_cmax[32][72];
    __shared__ uint64_t s_list[LISTCAP];
    __shared__ int s_n;

    const int x0 = blockIdx.x * 64;
    const int y0 = blockIdx.y * 32;
    const int b  = blockIdx.z;
    const int t  = threadIdx.x;
    const float* gb = gray + (size_t)b * Hn * Wn;
    const float* mb = mask + (size_t)b * Hn * Wn;

    if (t == 0) s_n = 0;

    const bool xedge = (blockIdx.x == 0) || (blockIdx.x == gridDim.x - 1);
    if (!xedge) {
        for (int l = t; l < 38 * 18; l += 256) {
            int r = l / 18, c4 = l % 18;
            int gy = y0 + r - 3;
            float4 v;
            if (gy >= 0 && gy < Hn) {
                const float4* gp = (const float4*)(gb + (size_t)gy * Wn + x0 - 4);
                const float4* mp = (const float4*)(mb + (size_t)gy * Wn + x0 - 4);
                float4 g = gp[c4], m = mp[c4];
                v = make_float4(g.x * m.x, g.y * m.y, g.z * m.z, g.w * m.w);
            } else {
                float ni = -__builtin_inff();
                v = make_float4(ni, ni, ni, ni);
            }
            *(float4*)&s_img[r][c4 * 4] = v;
        }
    } else {
        for (int l = t; l < 38 * 72; l += 256) {
            int r = l / 72, c = l % 72;
            int gy = y0 + r - 3, gx = x0 + c - 4;
            float v = -__builtin_inff();
            if (gy >= 0 && gy < Hn && gx >= 0 && gx < Wn) {
                int o = gy * Wn + gx;
                v = gb[o] * mb[o];
            }
            s_img[r][c] = v;
        }
    }
    __syncthreads();

    for (int l = t; l < 32 * 72; l += 256) {
        int r = l / 72, c = l % 72;
        float m = s_img[r][c];
#pragma unroll
        for (int d = 1; d < 7; ++d) m = fmaxf(m, s_img[r + d][c]);
        s_cmax[r][c] = m;
    }
    __syncthreads();

    for (int l = t; l < 32 * 64; l += 256) {
        int r = l >> 6, c = l & 63;
        float p = s_cmax[r][c + 1];
#pragma unroll
        for (int d = 2; d < 8; ++d) p = fmaxf(p, s_cmax[r][c + d]);
        float v = s_img[r + 3][c + 4];
        if (v == p && v > 0.1f) {
            uint32_t idx = (uint32_t)((y0 + r) * Wn + (x0 + c));
            uint64_t key = ((uint64_t)__float_as_uint(v) << 32) | (uint32_t)(~idx);
            int pos = atomicAdd(&s_n, 1);
            if (pos < LISTCAP) s_list[pos] = key;
        }
    }
    __syncthreads();

    int m = s_n; if (m > SLOTS) m = SLOTS;
    const int tile = blockIdx.y * gridDim.x + blockIdx.x;
    uint64_t* dst = slots + ((size_t)b * TILES + tile) * SLOTS;
    for (int i = t; i < m; i += 256) dst[i] = s_list[i];
    if (t == 0) counts[b * TILES + tile] = m;
}

// ---------------- Kernel 2: fused top-k + NMS, one block per batch ------------------
// Phases: LDS hist (global pass 1) -> shfl suffix scan (threshold bin T) -> scatter
// bins>=T into bin-grouped LDS slots (global pass 2, L2-resident) -> PARALLEL
// RANK-SCATTER sort (one thread per element: independent pipelined LDS reads, no
// dependent insertion chains) -> tie-run NMS -> compact scan -> output.
__global__ __launch_bounds__(1024) void topk_nms_kernel(const uint64_t* __restrict__ slots,
                                                        const int* __restrict__ counts,
                                                        float* __restrict__ kp_out,
                                                        float* __restrict__ sc_out) {
    __shared__ uint64_t keys[KEYSN];     // 32 KB (bin-grouped, unsorted within bin)
    __shared__ uint64_t keys2[NTOP];     // 16 KB (globally sorted top-2048)
    __shared__ int      hist[FBINS];     // 16 KB (then scatter cursors)
    __shared__ int      sfx[FBINS];      // 16 KB
    __shared__ int      tcnt[TILES];     // 1 KB
    __shared__ int      scanA[64];
    __shared__ uint32_t pairs[PAIRCAP];  // 8 KB
    __shared__ uint8_t  keep[NTOP];      // 2 KB
    __shared__ int      sel[KMAX];       // 2 KB
    __shared__ int      misc[4];

    const int b = blockIdx.x;
    const int t = threadIdx.x;
    const int lane = t & 63;
    const int w = t >> 6;
    const uint64_t* sb = slots + (size_t)b * TILES * SLOTS;

    if (t < TILES) tcnt[t] = counts[b * TILES + t];
    *(int4*)&hist[t << 2] = make_int4(0, 0, 0, 0);
    for (int i = t; i < NTOP; i += 1024) keys2[i] = 0ull;
    if (t < 4) misc[t] = 0;
    if (t < KMAX) sel[t] = -1;
    __syncthreads();

    // Phase A: histogram (global pass 1, coalesced; slots are L2-resident)
    for (int i = t; i < TILES * SLOTS; i += 1024) {
        int tile = i / SLOTS;
        int slot = i - tile * SLOTS;
        if (slot < tcnt[tile]) {
            uint32_t sbits = (uint32_t)(sb[i] >> 32);
            int bin = (int)(sbits >> 13) - FBASE;
            bin = bin < 0 ? 0 : (bin > FBINS - 1 ? FBINS - 1 : bin);
            atomicAdd(&hist[bin], 1);
        }
    }
    __syncthreads();

    // Phase B: hierarchical suffix scan over 4096 bins (thread t owns bins 4t..4t+3)
    const int base4 = t << 2;
    const int4 h4 = *(const int4*)&hist[base4];
    int loc = h4.x + h4.y + h4.z + h4.w;
    int x = loc;
#pragma unroll
    for (int d = 1; d < 64; d <<= 1) {
        int y = __shfl_down(x, d, 64);
        if (lane + d < 64) x += y;
    }
    if (lane == 0) scanA[w] = x;
    __syncthreads();
    if (w == 0) {
        int v = (lane < 16) ? scanA[lane] : 0;
#pragma unroll
        for (int d = 1; d < 16; d <<= 1) {
            int y = __shfl_down(v, d, 64);
            if (lane + d < 64) v += y;
        }
        if (lane < 16) scanA[lane] = v;
    }
    __syncthreads();
    const int total = scanA[0];
    const int target = total < NTOP ? total : NTOP;
    const int S_incl = x + ((w < 15) ? scanA[w + 1] : 0);

    int r = S_incl - loc;                    // sfx[base4+4]
    int s3 = r + h4.w;
    int s2 = s3 + h4.z;
    int s1 = s2 + h4.y;
    int s0 = s1 + h4.x;
    *(int4*)&sfx[base4]  = make_int4(s0, s1, s2, s3);
    *(int4*)&hist[base4] = make_int4(s1, s2, s3, r);    // scatter cursors
    if (s0 >= target && s1 < target) misc[2] = base4;
    if (s1 >= target && s2 < target) misc[2] = base4 + 1;
    if (s2 >= target && s3 < target) misc[2] = base4 + 2;
    if (s3 >= target && (base4 + 3 == FBINS - 1 || r < target)) misc[2] = base4 + 3;
    __syncthreads();
    const int T = misc[2];
    int cnt = sfx[T]; if (cnt > KEYSN) cnt = KEYSN;

    // Phase C: scatter selected bins into bin-grouped slots (global pass 2)
    for (int i = t; i < TILES * SLOTS; i += 1024) {
        int tile = i / SLOTS;
        int slot = i - tile * SLOTS;
        if (slot < tcnt[tile]) {
            uint64_t key = sb[i];
            uint32_t sbits = (uint32_t)(key >> 32);
            int bin = (int)(sbits >> 13) - FBASE;
            bin = bin < 0 ? 0 : (bin > FBINS - 1 ? FBINS - 1 : bin);
            if (bin >= T) {
                int pos = atomicAdd(&hist[bin], 1);
                if (pos < KEYSN) keys[pos] = key;
            }
        }
    }
    __syncthreads();

    // Phase D: parallel rank-scatter sort. Element e's rank = bin_start + #{greater in
    // bin}. Independent LDS reads (pipelined, no dependent chain); keys distinct
    // (unique pixel idx) => exact total order (score desc, idx asc).
    for (int e = t; e < cnt; e += 1024) {
        uint64_t key = keys[e];
        uint32_t sbits = (uint32_t)(key >> 32);
        int bin = (int)(sbits >> 13) - FBASE;
        bin = bin < 0 ? 0 : (bin > FBINS - 1 ? FBINS - 1 : bin);
        int a0 = (bin + 1 < FBINS) ? sfx[bin + 1] : 0;
        int e0 = sfx[bin]; if (e0 > KEYSN) e0 = KEYSN;
        int rank = a0;
        for (int q = a0; q < e0; ++q) rank += (keys[q] > key) ? 1 : 0;
        if (rank < NTOP) keys2[rank] = key;
    }
    __syncthreads();

    // Phase E: keep init + conflict pairs within equal-score runs only (two valid
    // candidates with dist<3 lie in each other's 7x7 window => equal pooled max)
    for (int j = t; j < NTOP; j += 1024) {
        uint32_t s = (uint32_t)(keys2[j] >> 32);
        keep[j] = (s != 0u) ? 1 : 0;
        if (s) {
            uint32_t idx = ~(uint32_t)keys2[j];
            int xq = (int)(idx & (Wn - 1)), yq = (int)(idx >> 10);
            for (int i = j - 1; i >= 0 && (uint32_t)(keys2[i] >> 32) == s; --i) {
                uint32_t idx2 = ~(uint32_t)keys2[i];
                int dx = xq - (int)(idx2 & (Wn - 1));
                int dy = yq - (int)(idx2 >> 10);
                if (dx * dx + dy * dy < 9) {        // dist < R=3, exact in integers
                    int p = atomicAdd(&misc[1], 1);
                    if (p < PAIRCAP) pairs[p] = ((uint32_t)j << 16) | (uint32_t)i;
                }
            }
        }
    }
    __syncthreads();

    if (t == 0) {   // sequential greedy resolve (tiny; canonical order via sort)
        int pc = misc[1]; if (pc > PAIRCAP) pc = PAIRCAP;
        for (int a = 1; a < pc; ++a) {
            uint32_t v = pairs[a]; int q = a - 1;
            while (q >= 0 && pairs[q] > v) { pairs[q + 1] = pairs[q]; --q; }
            pairs[q + 1] = v;
        }
        for (int a = 0; a < pc; ++a) {
            int j = (int)(pairs[a] >> 16), i = (int)(pairs[a] & 0xFFFF);
            if (keep[i]) keep[j] = 0;
        }
    }
    __syncthreads();

    // Phase F: compaction prefix scan (shfl hierarchy), select first 512 kept
    int j0 = 2 * t, j1 = j0 + 1;
    int k0 = keep[j0], k1 = keep[j1];
    int sum = k0 + k1;
    int xp = sum;
#pragma unroll
    for (int d = 1; d < 64; d <<= 1) {
        int y = __shfl_up(xp, d, 64);
        if (lane >= d) xp += y;
    }
    if (lane == 63) scanA[w] = xp;
    __syncthreads();
    if (w == 0) {
        int v = (lane < 16) ? scanA[lane] : 0;
#pragma unroll
        for (int d = 1; d < 16; d <<= 1) {
            int y = __shfl_up(v, d, 64);
            if (lane >= d) v += y;
        }
        if (lane < 16) scanA[lane] = v;
    }
    __syncthreads();
    int pre = xp + ((w > 0) ? scanA[w - 1] : 0);
    int ex = pre - sum;
    if (k0 && ex < KMAX) sel[ex] = j0;
    if (k1 && (ex + k0) < KMAX) sel[ex + k0] = j1;
    __syncthreads();

    if (t < KMAX) {
        int jj = sel[t];
        float xo = 0.f, yo = 0.f, so = 0.f;
        if (jj >= 0) {
            uint32_t idx = ~(uint32_t)keys2[jj];
            xo = (float)(idx & (Wn - 1));
            yo = (float)(idx >> 10);
            so = __uint_as_float((uint32_t)(keys2[jj] >> 32));
        }
        kp_out[(size_t)b * KMAX * 2 + 2 * t]     = xo;
        kp_out[(size_t)b * KMAX * 2 + 2 * t + 1] = yo;
        sc_out[(size_t)b * KMAX + t]             = so;
    }
}

extern "C" void kernel_launch(void* const* d_in, const int* in_sizes, int n_in,
                              void* d_out, int out_size, void* d_ws, size_t ws_size,
                              hipStream_t stream) {
    const float* gray = (const float*)d_in[0];
    const float* mask = (const float*)d_in[1];
    float* out = (float*)d_out;
    float* kp_out = out;                        // 16*512*2
    float* sc_out = out + (size_t)Bn * KMAX * 2;

    int*      counts = (int*)d_ws;                      // 16 KB, fully rewritten
    uint64_t* slots  = (uint64_t*)((char*)d_ws + 16384);// 3 MB, masked by counts

    dim3 g1(Wn / 64, Hn / 32, Bn);              // (16, 16, 16) = 4096 blocks
    detect_kernel<<<g1, 256, 0, stream>>>(gray, mask, slots, counts);
    topk_nms_kernel<<<Bn, 1024, 0, stream>>>(slots, counts, kp_out, sc_out);
}

// Round 8
// 56.329 us; speedup vs baseline: 1.9736x; 1.0124x over previous
//
#include <hip/hip_runtime.h>
#include <cstdint>
#include <cstddef>

#define Bn 16
#define Hn 512
#define Wn 1024
#define NTOP 2048
#define KMAX 512
#define PAIRCAP 2048
#define FBINS 4096
#define FBASE 126566      // (0x3DCCCCCD>>13); scores in (0.1,1) -> bins [0,3481]
#define KEYSN 4096
#define TILES 256         // tiles per batch: 16x16 grid of 64x32 tiles
#define SLOTS 96          // per-tile slot region (mean ~42 cand/tile)
#define LISTCAP 128

// ---------------- Kernel 1: local-max detect -> fixed per-tile slots ----------------
// Tile 64x32, LDS tile 38x72. ALL stencil phases float4 (ds_read_b128): round-7 PMC
// arithmetic showed the scalar version was LDS-issue-bound (~25 us of ds_read_b32
// pipe occupancy per CU). Vertical: 7 f4 reads per 4 outputs. Horizontal: van Herk
// suffix/prefix sliding max, 3 f4 cmax reads + 1 f4 center read per 4 outputs.
__global__ __launch_bounds__(256) void detect_kernel(const float* __restrict__ gray,
                                                     const float* __restrict__ mask,
                                                     uint64_t* __restrict__ slots,
                                                     int* __restrict__ counts) {
    __shared__ __align__(16) float s_img[38][72];   // col c <-> gx = x0 + c - 4
    __shared__ __align__(16) float s_cmax[32][72];
    __shared__ uint64_t s_list[LISTCAP];
    __shared__ int s_n;

    const int x0 = blockIdx.x * 64;
    const int y0 = blockIdx.y * 32;
    const int b  = blockIdx.z;
    const int t  = threadIdx.x;
    const float* gb = gray + (size_t)b * Hn * Wn;
    const float* mb = mask + (size_t)b * Hn * Wn;

    if (t == 0) s_n = 0;

    const bool xedge = (blockIdx.x == 0) || (blockIdx.x == gridDim.x - 1);
    if (!xedge) {
        for (int l = t; l < 38 * 18; l += 256) {
            int r = l / 18, c4 = l % 18;
            int gy = y0 + r - 3;
            float4 v;
            if (gy >= 0 && gy < Hn) {
                const float4* gp = (const float4*)(gb + (size_t)gy * Wn + x0 - 4);
                const float4* mp = (const float4*)(mb + (size_t)gy * Wn + x0 - 4);
                float4 g = gp[c4], m = mp[c4];
                v = make_float4(g.x * m.x, g.y * m.y, g.z * m.z, g.w * m.w);
            } else {
                float ni = -__builtin_inff();
                v = make_float4(ni, ni, ni, ni);
            }
            *(float4*)&s_img[r][c4 * 4] = v;
        }
    } else {
        for (int l = t; l < 38 * 72; l += 256) {
            int r = l / 72, c = l % 72;
            int gy = y0 + r - 3, gx = x0 + c - 4;
            float v = -__builtin_inff();
            if (gy >= 0 && gy < Hn && gx >= 0 && gx < Wn) {
                int o = gy * Wn + gx;
                v = gb[o] * mb[o];
            }
            s_img[r][c] = v;
        }
    }
    __syncthreads();

    // vertical max over 7, float4-wide: 32 rows x 18 col-groups
    for (int l = t; l < 32 * 18; l += 256) {
        int r = l / 18, c4 = l % 18;
        float4 m = *(const float4*)&s_img[r][c4 * 4];
#pragma unroll
        for (int d = 1; d < 7; ++d) {
            float4 v = *(const float4*)&s_img[r + d][c4 * 4];
            m.x = fmaxf(m.x, v.x); m.y = fmaxf(m.y, v.y);
            m.z = fmaxf(m.z, v.z); m.w = fmaxf(m.w, v.w);
        }
        *(float4*)&s_cmax[r][c4 * 4] = m;
    }
    __syncthreads();

    // horizontal sliding max over 7 (van Herk) + validity + append.
    // Output group: pixel cols 4*c4..4*c4+3 (c4 in [0,16)); a_i = cmax[4*c4 + i].
    for (int l = t; l < 32 * 16; l += 256) {
        int r = l >> 4, c4 = l & 15;
        float4 v0 = *(const float4*)&s_cmax[r][c4 * 4];       // a0..a3
        float4 v1 = *(const float4*)&s_cmax[r][c4 * 4 + 4];   // a4..a7
        float4 v2 = *(const float4*)&s_cmax[r][c4 * 4 + 8];   // a8..a11
        float s7 = v1.w;
        float s6 = fmaxf(v1.z, s7);
        float s5 = fmaxf(v1.y, s6);
        float s4 = fmaxf(v1.x, s5);
        float s3 = fmaxf(v0.w, s4);
        float s2 = fmaxf(v0.z, s3);
        float s1 = fmaxf(v0.y, s2);
        float p8 = v2.x;
        float p9 = fmaxf(p8, v2.y);
        float p10 = fmaxf(p9, v2.z);
        float o0 = s1;                 // max(a1..a7)
        float o1 = fmaxf(s2, p8);      // max(a2..a8)
        float o2 = fmaxf(s3, p9);      // max(a3..a9)
        float o3 = fmaxf(s4, p10);     // max(a4..a10)
        float4 cv = *(const float4*)&s_img[r + 3][c4 * 4 + 4];  // centers

        float vv[4] = {cv.x, cv.y, cv.z, cv.w};
        float pp[4] = {o0, o1, o2, o3};
#pragma unroll
        for (int k = 0; k < 4; ++k) {
            float v = vv[k];
            if (v == pp[k] && v > 0.1f) {
                uint32_t idx = (uint32_t)((y0 + r) * Wn + (x0 + c4 * 4 + k));
                uint64_t key = ((uint64_t)__float_as_uint(v) << 32) | (uint32_t)(~idx);
                int pos = atomicAdd(&s_n, 1);       // LDS atomic
                if (pos < LISTCAP) s_list[pos] = key;
            }
        }
    }
    __syncthreads();

    int m = s_n; if (m > SLOTS) m = SLOTS;
    const int tile = blockIdx.y * gridDim.x + blockIdx.x;
    uint64_t* dst = slots + ((size_t)b * TILES + tile) * SLOTS;
    for (int i = t; i < m; i += 256) dst[i] = s_list[i];
    if (t == 0) counts[b * TILES + tile] = m;
}

// ---------------- Kernel 2: fused top-k + NMS, one block per batch ------------------
// (byte-identical to round 7 for attribution)
__global__ __launch_bounds__(1024) void topk_nms_kernel(const uint64_t* __restrict__ slots,
                                                        const int* __restrict__ counts,
                                                        float* __restrict__ kp_out,
                                                        float* __restrict__ sc_out) {
    __shared__ uint64_t keys[KEYSN];
    __shared__ uint64_t keys2[NTOP];
    __shared__ int      hist[FBINS];
    __shared__ int      sfx[FBINS];
    __shared__ int      tcnt[TILES];
    __shared__ int      scanA[64];
    __shared__ uint32_t pairs[PAIRCAP];
    __shared__ uint8_t  keep[NTOP];
    __shared__ int      sel[KMAX];
    __shared__ int      misc[4];

    const int b = blockIdx.x;
    const int t = threadIdx.x;
    const int lane = t & 63;
    const int w = t >> 6;
    const uint64_t* sb = slots + (size_t)b * TILES * SLOTS;

    if (t < TILES) tcnt[t] = counts[b * TILES + t];
    *(int4*)&hist[t << 2] = make_int4(0, 0, 0, 0);
    for (int i = t; i < NTOP; i += 1024) keys2[i] = 0ull;
    if (t < 4) misc[t] = 0;
    if (t < KMAX) sel[t] = -1;
    __syncthreads();

    // Phase A: histogram (global pass 1)
    for (int i = t; i < TILES * SLOTS; i += 1024) {
        int tile = i / SLOTS;
        int slot = i - tile * SLOTS;
        if (slot < tcnt[tile]) {
            uint32_t sbits = (uint32_t)(sb[i] >> 32);
            int bin = (int)(sbits >> 13) - FBASE;
            bin = bin < 0 ? 0 : (bin > FBINS - 1 ? FBINS - 1 : bin);
            atomicAdd(&hist[bin], 1);
        }
    }
    __syncthreads();

    // Phase B: hierarchical suffix scan over 4096 bins
    const int base4 = t << 2;
    const int4 h4 = *(const int4*)&hist[base4];
    int loc = h4.x + h4.y + h4.z + h4.w;
    int x = loc;
#pragma unroll
    for (int d = 1; d < 64; d <<= 1) {
        int y = __shfl_down(x, d, 64);
        if (lane + d < 64) x += y;
    }
    if (lane == 0) scanA[w] = x;
    __syncthreads();
    if (w == 0) {
        int v = (lane < 16) ? scanA[lane] : 0;
#pragma unroll
        for (int d = 1; d < 16; d <<= 1) {
            int y = __shfl_down(v, d, 64);
            if (lane + d < 64) v += y;
        }
        if (lane < 16) scanA[lane] = v;
    }
    __syncthreads();
    const int total = scanA[0];
    const int target = total < NTOP ? total : NTOP;
    const int S_incl = x + ((w < 15) ? scanA[w + 1] : 0);

    int r = S_incl - loc;
    int s3 = r + h4.w;
    int s2 = s3 + h4.z;
    int s1 = s2 + h4.y;
    int s0 = s1 + h4.x;
    *(int4*)&sfx[base4]  = make_int4(s0, s1, s2, s3);
    *(int4*)&hist[base4] = make_int4(s1, s2, s3, r);
    if (s0 >= target && s1 < target) misc[2] = base4;
    if (s1 >= target && s2 < target) misc[2] = base4 + 1;
    if (s2 >= target && s3 < target) misc[2] = base4 + 2;
    if (s3 >= target && (base4 + 3 == FBINS - 1 || r < target)) misc[2] = base4 + 3;
    __syncthreads();
    const int T = misc[2];
    int cnt = sfx[T]; if (cnt > KEYSN) cnt = KEYSN;

    // Phase C: scatter selected bins into bin-grouped slots (global pass 2)
    for (int i = t; i < TILES * SLOTS; i += 1024) {
        int tile = i / SLOTS;
        int slot = i - tile * SLOTS;
        if (slot < tcnt[tile]) {
            uint64_t key = sb[i];
            uint32_t sbits = (uint32_t)(key >> 32);
            int bin = (int)(sbits >> 13) - FBASE;
            bin = bin < 0 ? 0 : (bin > FBINS - 1 ? FBINS - 1 : bin);
            if (bin >= T) {
                int pos = atomicAdd(&hist[bin], 1);
                if (pos < KEYSN) keys[pos] = key;
            }
        }
    }
    __syncthreads();

    // Phase D: parallel rank-scatter sort
    for (int e = t; e < cnt; e += 1024) {
        uint64_t key = keys[e];
        uint32_t sbits = (uint32_t)(key >> 32);
        int bin = (int)(sbits >> 13) - FBASE;
        bin = bin < 0 ? 0 : (bin > FBINS - 1 ? FBINS - 1 : bin);
        int a0 = (bin + 1 < FBINS) ? sfx[bin + 1] : 0;
        int e0 = sfx[bin]; if (e0 > KEYSN) e0 = KEYSN;
        int rank = a0;
        for (int q = a0; q < e0; ++q) rank += (keys[q] > key) ? 1 : 0;
        if (rank < NTOP) keys2[rank] = key;
    }
    __syncthreads();

    // Phase E: keep init + conflict pairs within equal-score runs only
    for (int j = t; j < NTOP; j += 1024) {
        uint32_t s = (uint32_t)(keys2[j] >> 32);
        keep[j] = (s != 0u) ? 1 : 0;
        if (s) {
            uint32_t idx = ~(uint32_t)keys2[j];
            int xq = (int)(idx & (Wn - 1)), yq = (int)(idx >> 10);
            for (int i = j - 1; i >= 0 && (uint32_t)(keys2[i] >> 32) == s; --i) {
                uint32_t idx2 = ~(uint32_t)keys2[i];
                int dx = xq - (int)(idx2 & (Wn - 1));
                int dy = yq - (int)(idx2 >> 10);
                if (dx * dx + dy * dy < 9) {
                    int p = atomicAdd(&misc[1], 1);
                    if (p < PAIRCAP) pairs[p] = ((uint32_t)j << 16) | (uint32_t)i;
                }
            }
        }
    }
    __syncthreads();

    if (t == 0) {
        int pc = misc[1]; if (pc > PAIRCAP) pc = PAIRCAP;
        for (int a = 1; a < pc; ++a) {
            uint32_t v = pairs[a]; int q = a - 1;
            while (q >= 0 && pairs[q] > v) { pairs[q + 1] = pairs[q]; --q; }
            pairs[q + 1] = v;
        }
        for (int a = 0; a < pc; ++a) {
            int j = (int)(pairs[a] >> 16), i = (int)(pairs[a] & 0xFFFF);
            if (keep[i]) keep[j] = 0;
        }
    }
    __syncthreads();

    // Phase F: compaction prefix scan, select first 512 kept
    int j0 = 2 * t, j1 = j0 + 1;
    int k0 = keep[j0], k1 = keep[j1];
    int sum = k0 + k1;
    int xp = sum;
#pragma unroll
    for (int d = 1; d < 64; d <<= 1) {
        int y = __shfl_up(xp, d, 64);
        if (lane >= d) xp += y;
    }
    if (lane == 63) scanA[w] = xp;
    __syncthreads();
    if (w == 0) {
        int v = (lane < 16) ? scanA[lane] : 0;
#pragma unroll
        for (int d = 1; d < 16; d <<= 1) {
            int y = __shfl_up(v, d, 64);
            if (lane >= d) v += y;
        }
        if (lane < 16) scanA[lane] = v;
    }
    __syncthreads();
    int pre = xp + ((w > 0) ? scanA[w - 1] : 0);
    int ex = pre - sum;
    if (k0 && ex < KMAX) sel[ex] = j0;
    if (k1 && (ex + k0) < KMAX) sel[ex + k0] = j1;
    __syncthreads();

    if (t < KMAX) {
        int jj = sel[t];
        float xo = 0.f, yo = 0.f, so = 0.f;
        if (jj >= 0) {
            uint32_t idx = ~(uint32_t)keys2[jj];
            xo = (float)(idx & (Wn - 1));
            yo = (float)(idx >> 10);
            so = __uint_as_float((uint32_t)(keys2[jj] >> 32));
        }
        kp_out[(size_t)b * KMAX * 2 + 2 * t]     = xo;
        kp_out[(size_t)b * KMAX * 2 + 2 * t + 1] = yo;
        sc_out[(size_t)b * KMAX + t]             = so;
    }
}

extern "C" void kernel_launch(void* const* d_in, const int* in_sizes, int n_in,
                              void* d_out, int out_size, void* d_ws, size_t ws_size,
                              hipStream_t stream) {
    const float* gray = (const float*)d_in[0];
    const float* mask = (const float*)d_in[1];
    float* out = (float*)d_out;
    float* kp_out = out;                        // 16*512*2
    float* sc_out = out + (size_t)Bn * KMAX * 2;

    int*      counts = (int*)d_ws;                      // 16 KB, fully rewritten
    uint64_t* slots  = (uint64_t*)((char*)d_ws + 16384);// 3 MB, masked by counts

    dim3 g1(Wn / 64, Hn / 32, Bn);              // (16, 16, 16) = 4096 blocks
    detect_kernel<<<g1, 256, 0, stream>>>(gray, mask, slots, counts);
    topk_nms_kernel<<<Bn, 1024, 0, stream>>>(slots, counts, kp_out, sc_out);
}

// Round 9
// 50.628 us; speedup vs baseline: 2.1958x; 1.1126x over previous
//
#include <hip/hip_runtime.h>
#include <cstdint>
#include <cstddef>

#define Bn 16
#define Hn 512
#define Wn 1024
#define NTOP 2048
#define KMAX 512
#define PAIRCAP 2048
#define FBINS 4096
#define FBASE 126566      // (0x3DCCCCCD>>13); scores in (0.1,1) -> bins [0,3481]
#define KEYSN 4096
#define TILES 256         // tiles per batch: 16x16 grid of 64x32 tiles
#define SLOTS 96          // per-tile slot region (mean ~42 cand/tile)
#define LISTCAP 128

// ---------------- Kernel 1: local-max detect -> fixed per-tile slots ----------------
// Byte-identical stencil to round 8; only change: unused slots are ZERO-FILLED so the
// consumer uses key!=0 as validity (no counts array, no div-by-96 masking).
__global__ __launch_bounds__(256) void detect_kernel(const float* __restrict__ gray,
                                                     const float* __restrict__ mask,
                                                     uint64_t* __restrict__ slots) {
    __shared__ __align__(16) float s_img[38][72];   // col c <-> gx = x0 + c - 4
    __shared__ __align__(16) float s_cmax[32][72];
    __shared__ uint64_t s_list[LISTCAP];
    __shared__ int s_n;

    const int x0 = blockIdx.x * 64;
    const int y0 = blockIdx.y * 32;
    const int b  = blockIdx.z;
    const int t  = threadIdx.x;
    const float* gb = gray + (size_t)b * Hn * Wn;
    const float* mb = mask + (size_t)b * Hn * Wn;

    if (t == 0) s_n = 0;

    const bool xedge = (blockIdx.x == 0) || (blockIdx.x == gridDim.x - 1);
    if (!xedge) {
        for (int l = t; l < 38 * 18; l += 256) {
            int r = l / 18, c4 = l % 18;
            int gy = y0 + r - 3;
            float4 v;
            if (gy >= 0 && gy < Hn) {
                const float4* gp = (const float4*)(gb + (size_t)gy * Wn + x0 - 4);
                const float4* mp = (const float4*)(mb + (size_t)gy * Wn + x0 - 4);
                float4 g = gp[c4], m = mp[c4];
                v = make_float4(g.x * m.x, g.y * m.y, g.z * m.z, g.w * m.w);
            } else {
                float ni = -__builtin_inff();
                v = make_float4(ni, ni, ni, ni);
            }
            *(float4*)&s_img[r][c4 * 4] = v;
        }
    } else {
        for (int l = t; l < 38 * 72; l += 256) {
            int r = l / 72, c = l % 72;
            int gy = y0 + r - 3, gx = x0 + c - 4;
            float v = -__builtin_inff();
            if (gy >= 0 && gy < Hn && gx >= 0 && gx < Wn) {
                int o = gy * Wn + gx;
                v = gb[o] * mb[o];
            }
            s_img[r][c] = v;
        }
    }
    __syncthreads();

    // vertical max over 7, float4-wide
    for (int l = t; l < 32 * 18; l += 256) {
        int r = l / 18, c4 = l % 18;
        float4 m = *(const float4*)&s_img[r][c4 * 4];
#pragma unroll
        for (int d = 1; d < 7; ++d) {
            float4 v = *(const float4*)&s_img[r + d][c4 * 4];
            m.x = fmaxf(m.x, v.x); m.y = fmaxf(m.y, v.y);
            m.z = fmaxf(m.z, v.z); m.w = fmaxf(m.w, v.w);
        }
        *(float4*)&s_cmax[r][c4 * 4] = m;
    }
    __syncthreads();

    // horizontal sliding max over 7 (van Herk) + validity + append
    for (int l = t; l < 32 * 16; l += 256) {
        int r = l >> 4, c4 = l & 15;
        float4 v0 = *(const float4*)&s_cmax[r][c4 * 4];
        float4 v1 = *(const float4*)&s_cmax[r][c4 * 4 + 4];
        float4 v2 = *(const float4*)&s_cmax[r][c4 * 4 + 8];
        float s7 = v1.w;
        float s6 = fmaxf(v1.z, s7);
        float s5 = fmaxf(v1.y, s6);
        float s4 = fmaxf(v1.x, s5);
        float s3 = fmaxf(v0.w, s4);
        float s2 = fmaxf(v0.z, s3);
        float s1 = fmaxf(v0.y, s2);
        float p8 = v2.x;
        float p9 = fmaxf(p8, v2.y);
        float p10 = fmaxf(p9, v2.z);
        float o0 = s1;
        float o1 = fmaxf(s2, p8);
        float o2 = fmaxf(s3, p9);
        float o3 = fmaxf(s4, p10);
        float4 cv = *(const float4*)&s_img[r + 3][c4 * 4 + 4];

        float vv[4] = {cv.x, cv.y, cv.z, cv.w};
        float pp[4] = {o0, o1, o2, o3};
#pragma unroll
        for (int k = 0; k < 4; ++k) {
            float v = vv[k];
            if (v == pp[k] && v > 0.1f) {
                uint32_t idx = (uint32_t)((y0 + r) * Wn + (x0 + c4 * 4 + k));
                uint64_t key = ((uint64_t)__float_as_uint(v) << 32) | (uint32_t)(~idx);
                int pos = atomicAdd(&s_n, 1);       // LDS atomic
                if (pos < LISTCAP) s_list[pos] = key;
            }
        }
    }
    __syncthreads();

    int m = s_n; if (m > SLOTS) m = SLOTS;
    const int tile = blockIdx.y * gridDim.x + blockIdx.x;
    uint64_t* dst = slots + ((size_t)b * TILES + tile) * SLOTS;
    for (int i = t; i < m; i += 256) dst[i] = s_list[i];
    for (int i = m + t; i < SLOTS; i += 256) dst[i] = 0ull;   // zero sentinel
}

// ---------------- Kernel 2: fused top-k + NMS, one block per batch ------------------
// Both global passes are now 12 x ulonglong2 vector loads with key!=0 validity (no
// division, no count masking). Phases: LDS hist -> shfl suffix scan (threshold bin T)
// -> scatter into bin-grouped LDS slots -> parallel rank-scatter sort -> tie-run NMS
// -> compact scan -> output.
__global__ __launch_bounds__(1024) void topk_nms_kernel(const uint64_t* __restrict__ slots,
                                                        float* __restrict__ kp_out,
                                                        float* __restrict__ sc_out) {
    __shared__ uint64_t keys[KEYSN];
    __shared__ uint64_t keys2[NTOP];
    __shared__ int      hist[FBINS];
    __shared__ int      sfx[FBINS];
    __shared__ int      scanA[64];
    __shared__ uint32_t pairs[PAIRCAP];
    __shared__ uint8_t  keep[NTOP];
    __shared__ int      sel[KMAX];
    __shared__ int      misc[4];

    const int b = blockIdx.x;
    const int t = threadIdx.x;
    const int lane = t & 63;
    const int w = t >> 6;
    const ulonglong2* sb2 = (const ulonglong2*)(slots + (size_t)b * TILES * SLOTS);

    *(int4*)&hist[t << 2] = make_int4(0, 0, 0, 0);
    for (int i = t; i < NTOP; i += 1024) keys2[i] = 0ull;
    if (t < 4) misc[t] = 0;
    if (t < KMAX) sel[t] = -1;
    __syncthreads();

    // Phase A: histogram (global pass 1, 12 vector iterations)
    for (int i = t; i < TILES * SLOTS / 2; i += 1024) {
        ulonglong2 kp = sb2[i];
#pragma unroll
        for (int h = 0; h < 2; ++h) {
            uint32_t sbits = (uint32_t)((h ? kp.y : kp.x) >> 32);
            if (sbits) {
                int bin = (int)(sbits >> 13) - FBASE;
                bin = bin < 0 ? 0 : (bin > FBINS - 1 ? FBINS - 1 : bin);
                atomicAdd(&hist[bin], 1);
            }
        }
    }
    __syncthreads();

    // Phase B: hierarchical suffix scan over 4096 bins (thread t owns bins 4t..4t+3)
    const int base4 = t << 2;
    const int4 h4 = *(const int4*)&hist[base4];
    int loc = h4.x + h4.y + h4.z + h4.w;
    int x = loc;
#pragma unroll
    for (int d = 1; d < 64; d <<= 1) {
        int y = __shfl_down(x, d, 64);
        if (lane + d < 64) x += y;
    }
    if (lane == 0) scanA[w] = x;
    __syncthreads();
    if (w == 0) {
        int v = (lane < 16) ? scanA[lane] : 0;
#pragma unroll
        for (int d = 1; d < 16; d <<= 1) {
            int y = __shfl_down(v, d, 64);
            if (lane + d < 64) v += y;
        }
        if (lane < 16) scanA[lane] = v;
    }
    __syncthreads();
    const int total = scanA[0];
    const int target = total < NTOP ? total : NTOP;
    const int S_incl = x + ((w < 15) ? scanA[w + 1] : 0);

    int r = S_incl - loc;
    int s3 = r + h4.w;
    int s2 = s3 + h4.z;
    int s1 = s2 + h4.y;
    int s0 = s1 + h4.x;
    *(int4*)&sfx[base4]  = make_int4(s0, s1, s2, s3);
    *(int4*)&hist[base4] = make_int4(s1, s2, s3, r);    // scatter cursors
    if (s0 >= target && s1 < target) misc[2] = base4;
    if (s1 >= target && s2 < target) misc[2] = base4 + 1;
    if (s2 >= target && s3 < target) misc[2] = base4 + 2;
    if (s3 >= target && (base4 + 3 == FBINS - 1 || r < target)) misc[2] = base4 + 3;
    __syncthreads();
    const int T = misc[2];
    int cnt = sfx[T]; if (cnt > KEYSN) cnt = KEYSN;

    // Phase C: scatter selected bins into bin-grouped slots (global pass 2)
    for (int i = t; i < TILES * SLOTS / 2; i += 1024) {
        ulonglong2 kp = sb2[i];
#pragma unroll
        for (int h = 0; h < 2; ++h) {
            uint64_t key = h ? kp.y : kp.x;
            uint32_t sbits = (uint32_t)(key >> 32);
            if (sbits) {
                int bin = (int)(sbits >> 13) - FBASE;
                bin = bin < 0 ? 0 : (bin > FBINS - 1 ? FBINS - 1 : bin);
                if (bin >= T) {
                    int pos = atomicAdd(&hist[bin], 1);
                    if (pos < KEYSN) keys[pos] = key;
                }
            }
        }
    }
    __syncthreads();

    // Phase D: parallel rank-scatter sort (keys distinct => exact total order)
    for (int e = t; e < cnt; e += 1024) {
        uint64_t key = keys[e];
        uint32_t sbits = (uint32_t)(key >> 32);
        int bin = (int)(sbits >> 13) - FBASE;
        bin = bin < 0 ? 0 : (bin > FBINS - 1 ? FBINS - 1 : bin);
        int a0 = (bin + 1 < FBINS) ? sfx[bin + 1] : 0;
        int e0 = sfx[bin]; if (e0 > KEYSN) e0 = KEYSN;
        int rank = a0;
        for (int q = a0; q < e0; ++q) rank += (keys[q] > key) ? 1 : 0;
        if (rank < NTOP) keys2[rank] = key;
    }
    __syncthreads();

    // Phase E: keep init + conflict pairs within equal-score runs only (two valid
    // candidates with dist<3 lie in each other's 7x7 window => equal pooled max)
    for (int j = t; j < NTOP; j += 1024) {
        uint32_t s = (uint32_t)(keys2[j] >> 32);
        keep[j] = (s != 0u) ? 1 : 0;
        if (s) {
            uint32_t idx = ~(uint32_t)keys2[j];
            int xq = (int)(idx & (Wn - 1)), yq = (int)(idx >> 10);
            for (int i = j - 1; i >= 0 && (uint32_t)(keys2[i] >> 32) == s; --i) {
                uint32_t idx2 = ~(uint32_t)keys2[i];
                int dx = xq - (int)(idx2 & (Wn - 1));
                int dy = yq - (int)(idx2 >> 10);
                if (dx * dx + dy * dy < 9) {        // dist < R=3, exact in integers
                    int p = atomicAdd(&misc[1], 1);
                    if (p < PAIRCAP) pairs[p] = ((uint32_t)j << 16) | (uint32_t)i;
                }
            }
        }
    }
    __syncthreads();

    if (t == 0) {   // sequential greedy resolve (tiny; canonical order via sort)
        int pc = misc[1]; if (pc > PAIRCAP) pc = PAIRCAP;
        for (int a = 1; a < pc; ++a) {
            uint32_t v = pairs[a]; int q = a - 1;
            while (q >= 0 && pairs[q] > v) { pairs[q + 1] = pairs[q]; --q; }
            pairs[q + 1] = v;
        }
        for (int a = 0; a < pc; ++a) {
            int j = (int)(pairs[a] >> 16), i = (int)(pairs[a] & 0xFFFF);
            if (keep[i]) keep[j] = 0;
        }
    }
    __syncthreads();

    // Phase F: compaction prefix scan, select first 512 kept
    int j0 = 2 * t, j1 = j0 + 1;
    int k0 = keep[j0], k1 = keep[j1];
    int sum = k0 + k1;
    int xp = sum;
#pragma unroll
    for (int d = 1; d < 64; d <<= 1) {
        int y = __shfl_up(xp, d, 64);
        if (lane >= d) xp += y;
    }
    if (lane == 63) scanA[w] = xp;
    __syncthreads();
    if (w == 0) {
        int v = (lane < 16) ? scanA[lane] : 0;
#pragma unroll
        for (int d = 1; d < 16; d <<= 1) {
            int y = __shfl_up(v, d, 64);
            if (lane >= d) v += y;
        }
        if (lane < 16) scanA[lane] = v;
    }
    __syncthreads();
    int pre = xp + ((w > 0) ? scanA[w - 1] : 0);
    int ex = pre - sum;
    if (k0 && ex < KMAX) sel[ex] = j0;
    if (k1 && (ex + k0) < KMAX) sel[ex + k0] = j1;
    __syncthreads();

    if (t < KMAX) {
        int jj = sel[t];
        float xo = 0.f, yo = 0.f, so = 0.f;
        if (jj >= 0) {
            uint32_t idx = ~(uint32_t)keys2[jj];
            xo = (float)(idx & (Wn - 1));
            yo = (float)(idx >> 10);
            so = __uint_as_float((uint32_t)(keys2[jj] >> 32));
        }
        kp_out[(size_t)b * KMAX * 2 + 2 * t]     = xo;
        kp_out[(size_t)b * KMAX * 2 + 2 * t + 1] = yo;
        sc_out[(size_t)b * KMAX + t]             = so;
    }
}

extern "C" void kernel_launch(void* const* d_in, const int* in_sizes, int n_in,
                              void* d_out, int out_size, void* d_ws, size_t ws_size,
                              hipStream_t stream) {
    const float* gray = (const float*)d_in[0];
    const float* mask = (const float*)d_in[1];
    float* out = (float*)d_out;
    float* kp_out = out;                        // 16*512*2
    float* sc_out = out + (size_t)Bn * KMAX * 2;

    uint64_t* slots = (uint64_t*)d_ws;          // 3 MB, fully rewritten each call

    dim3 g1(Wn / 64, Hn / 32, Bn);              // (16, 16, 16) = 4096 blocks
    detect_kernel<<<g1, 256, 0, stream>>>(gray, mask, slots);
    topk_nms_kernel<<<Bn, 1024, 0, stream>>>(slots, kp_out, sc_out);
}

// Round 10
// 45.033 us; speedup vs baseline: 2.4687x; 1.1242x over previous
//
#include <hip/hip_runtime.h>
#include <cstdint>
#include <cstddef>

#define Bn 16
#define Hn 512
#define Wn 1024
#define NTOP 2048
#define KMAX 512
#define PAIRCAP 2048
#define FBINS 4096
#define FBASE 126566      // (0x3DCCCCCD>>13); scores in (0.1,1) -> bins [0,3481]
#define KEYSN 4096
#define XS 18             // x strips: 58 output cols each (64-lane read, 3+3 halo)
#define XW 58
#define SLOTS_B 256       // per-block slot region (mean ~149 cand; repulsive dist)
#define BLKS (XS * 4)     // 72 blocks per batch
#define NSLOT (BLKS * SLOTS_B)   // 18432 entries/batch

// ---------------- Kernel 1: barrier-free register-column local-max detect ----------
// Grid (18,4,16), 256 threads = 4 waves. Wave w: output rows yB*128+32w .. +31,
// cols 58*s .. (lane = col offset; lanes 0-2 and 61-63 are halo). The 38-row column
// (img = gray*mask, OOB = -inf) lives in registers: no LDS tile, no barriers.
// Vertical 7-max: 6 fmax/row. Horizontal 7-max: sliding window via 4 shuffles.
// Candidates -> per-block LDS list -> zero-filled fixed slot region (key!=0 = valid).
__global__ __launch_bounds__(256) void detect_kernel(const float* __restrict__ gray,
                                                     const float* __restrict__ mask,
                                                     uint64_t* __restrict__ slots) {
    __shared__ uint64_t s_list[SLOTS_B];
    __shared__ int s_n;

    const int s    = blockIdx.x;
    const int yB   = blockIdx.y;
    const int b    = blockIdx.z;
    const int t    = threadIdx.x;
    const int lane = t & 63;
    const int w    = t >> 6;
    const int col  = s * XW - 3 + lane;
    const int ybase = yB * 128 + w * 32;

    if (t == 0) s_n = 0;
    __syncthreads();

    const float* gb = gray + (size_t)b * Hn * Wn;
    const float* mb = mask + (size_t)b * Hn * Wn;
    const int colc = col < 0 ? 0 : (col >= Wn ? Wn - 1 : col);
    const bool colok = (col >= 0) && (col < Wn);
    const float NINF = -__builtin_inff();

    float im[38];
#pragma unroll
    for (int rr = 0; rr < 38; ++rr) {
        int gy = ybase - 3 + rr;                 // wave-uniform
        int gyc = gy < 0 ? 0 : (gy >= Hn ? Hn - 1 : gy);
        size_t o = (size_t)gyc * Wn + colc;
        float val = gb[o] * mb[o];
        im[rr] = (colok && gy >= 0 && gy < Hn) ? val : NINF;
    }

#pragma unroll
    for (int r = 0; r < 32; ++r) {
        // vertical max over rows r..r+6 (center row = ybase + r)
        float v7 = fmaxf(fmaxf(fmaxf(im[r], im[r + 1]), fmaxf(im[r + 2], im[r + 3])),
                         fmaxf(fmaxf(im[r + 4], im[r + 5]), im[r + 6]));
        // horizontal sliding max over lanes l-3..l+3
        float s1 = fmaxf(v7, __shfl_down(v7, 1, 64));
        float s2 = fmaxf(s1, __shfl_down(s1, 2, 64));
        float s3 = fmaxf(s2, __shfl_down(s2, 3, 64));   // max lanes l..l+6
        float h  = __shfl_up(s3, 3, 64);                // max lanes l-3..l+3
        float v  = im[r + 3];
        if (lane >= 3 && lane <= 60 && col < Wn && v == h && v > 0.1f) {
            uint32_t idx = (uint32_t)((ybase + r) * Wn + col);
            uint64_t key = ((uint64_t)__float_as_uint(v) << 32) | (uint32_t)(~idx);
            int pos = atomicAdd(&s_n, 1);               // LDS atomic
            if (pos < SLOTS_B) s_list[pos] = key;
        }
    }
    __syncthreads();

    int m = s_n; if (m > SLOTS_B) m = SLOTS_B;
    const int blk = yB * XS + s;
    uint64_t* dst = slots + ((size_t)b * BLKS + blk) * SLOTS_B;
    dst[t] = (t < m) ? s_list[t] : 0ull;                // SLOTS_B == blockDim
}

// ---------------- Kernel 2: fused top-k + NMS, one block per batch ------------------
// (byte-identical to round 9 except slot count 18432; ulonglong2 passes, key!=0 valid)
__global__ __launch_bounds__(1024) void topk_nms_kernel(const uint64_t* __restrict__ slots,
                                                        float* __restrict__ kp_out,
                                                        float* __restrict__ sc_out) {
    __shared__ uint64_t keys[KEYSN];
    __shared__ uint64_t keys2[NTOP];
    __shared__ int      hist[FBINS];
    __shared__ int      sfx[FBINS];
    __shared__ int      scanA[64];
    __shared__ uint32_t pairs[PAIRCAP];
    __shared__ uint8_t  keep[NTOP];
    __shared__ int      sel[KMAX];
    __shared__ int      misc[4];

    const int b = blockIdx.x;
    const int t = threadIdx.x;
    const int lane = t & 63;
    const int w = t >> 6;
    const ulonglong2* sb2 = (const ulonglong2*)(slots + (size_t)b * NSLOT);

    *(int4*)&hist[t << 2] = make_int4(0, 0, 0, 0);
    for (int i = t; i < NTOP; i += 1024) keys2[i] = 0ull;
    if (t < 4) misc[t] = 0;
    if (t < KMAX) sel[t] = -1;
    __syncthreads();

    // Phase A: histogram (global pass 1, 9 vector iterations)
    for (int i = t; i < NSLOT / 2; i += 1024) {
        ulonglong2 kp = sb2[i];
#pragma unroll
        for (int h = 0; h < 2; ++h) {
            uint32_t sbits = (uint32_t)((h ? kp.y : kp.x) >> 32);
            if (sbits) {
                int bin = (int)(sbits >> 13) - FBASE;
                bin = bin < 0 ? 0 : (bin > FBINS - 1 ? FBINS - 1 : bin);
                atomicAdd(&hist[bin], 1);
            }
        }
    }
    __syncthreads();

    // Phase B: hierarchical suffix scan over 4096 bins (thread t owns bins 4t..4t+3)
    const int base4 = t << 2;
    const int4 h4 = *(const int4*)&hist[base4];
    int loc = h4.x + h4.y + h4.z + h4.w;
    int x = loc;
#pragma unroll
    for (int d = 1; d < 64; d <<= 1) {
        int y = __shfl_down(x, d, 64);
        if (lane + d < 64) x += y;
    }
    if (lane == 0) scanA[w] = x;
    __syncthreads();
    if (w == 0) {
        int v = (lane < 16) ? scanA[lane] : 0;
#pragma unroll
        for (int d = 1; d < 16; d <<= 1) {
            int y = __shfl_down(v, d, 64);
            if (lane + d < 64) v += y;
        }
        if (lane < 16) scanA[lane] = v;
    }
    __syncthreads();
    const int total = scanA[0];
    const int target = total < NTOP ? total : NTOP;
    const int S_incl = x + ((w < 15) ? scanA[w + 1] : 0);

    int r = S_incl - loc;
    int s3 = r + h4.w;
    int s2 = s3 + h4.z;
    int s1 = s2 + h4.y;
    int s0 = s1 + h4.x;
    *(int4*)&sfx[base4]  = make_int4(s0, s1, s2, s3);
    *(int4*)&hist[base4] = make_int4(s1, s2, s3, r);    // scatter cursors
    if (s0 >= target && s1 < target) misc[2] = base4;
    if (s1 >= target && s2 < target) misc[2] = base4 + 1;
    if (s2 >= target && s3 < target) misc[2] = base4 + 2;
    if (s3 >= target && (base4 + 3 == FBINS - 1 || r < target)) misc[2] = base4 + 3;
    __syncthreads();
    const int T = misc[2];
    int cnt = sfx[T]; if (cnt > KEYSN) cnt = KEYSN;

    // Phase C: scatter selected bins into bin-grouped slots (global pass 2)
    for (int i = t; i < NSLOT / 2; i += 1024) {
        ulonglong2 kp = sb2[i];
#pragma unroll
        for (int h = 0; h < 2; ++h) {
            uint64_t key = h ? kp.y : kp.x;
            uint32_t sbits = (uint32_t)(key >> 32);
            if (sbits) {
                int bin = (int)(sbits >> 13) - FBASE;
                bin = bin < 0 ? 0 : (bin > FBINS - 1 ? FBINS - 1 : bin);
                if (bin >= T) {
                    int pos = atomicAdd(&hist[bin], 1);
                    if (pos < KEYSN) keys[pos] = key;
                }
            }
        }
    }
    __syncthreads();

    // Phase D: parallel rank-scatter sort (keys distinct => exact total order)
    for (int e = t; e < cnt; e += 1024) {
        uint64_t key = keys[e];
        uint32_t sbits = (uint32_t)(key >> 32);
        int bin = (int)(sbits >> 13) - FBASE;
        bin = bin < 0 ? 0 : (bin > FBINS - 1 ? FBINS - 1 : bin);
        int a0 = (bin + 1 < FBINS) ? sfx[bin + 1] : 0;
        int e0 = sfx[bin]; if (e0 > KEYSN) e0 = KEYSN;
        int rank = a0;
        for (int q = a0; q < e0; ++q) rank += (keys[q] > key) ? 1 : 0;
        if (rank < NTOP) keys2[rank] = key;
    }
    __syncthreads();

    // Phase E: keep init + conflict pairs within equal-score runs only (two valid
    // candidates with dist<3 lie in each other's 7x7 window => equal pooled max)
    for (int j = t; j < NTOP; j += 1024) {
        uint32_t s = (uint32_t)(keys2[j] >> 32);
        keep[j] = (s != 0u) ? 1 : 0;
        if (s) {
            uint32_t idx = ~(uint32_t)keys2[j];
            int xq = (int)(idx & (Wn - 1)), yq = (int)(idx >> 10);
            for (int i = j - 1; i >= 0 && (uint32_t)(keys2[i] >> 32) == s; --i) {
                uint32_t idx2 = ~(uint32_t)keys2[i];
                int dx = xq - (int)(idx2 & (Wn - 1));
                int dy = yq - (int)(idx2 >> 10);
                if (dx * dx + dy * dy < 9) {        // dist < R=3, exact in integers
                    int p = atomicAdd(&misc[1], 1);
                    if (p < PAIRCAP) pairs[p] = ((uint32_t)j << 16) | (uint32_t)i;
                }
            }
        }
    }
    __syncthreads();

    if (t == 0) {   // sequential greedy resolve (tiny; canonical order via sort)
        int pc = misc[1]; if (pc > PAIRCAP) pc = PAIRCAP;
        for (int a = 1; a < pc; ++a) {
            uint32_t v = pairs[a]; int q = a - 1;
            while (q >= 0 && pairs[q] > v) { pairs[q + 1] = pairs[q]; --q; }
            pairs[q + 1] = v;
        }
        for (int a = 0; a < pc; ++a) {
            int j = (int)(pairs[a] >> 16), i = (int)(pairs[a] & 0xFFFF);
            if (keep[i]) keep[j] = 0;
        }
    }
    __syncthreads();

    // Phase F: compaction prefix scan, select first 512 kept
    int j0 = 2 * t, j1 = j0 + 1;
    int k0 = keep[j0], k1 = keep[j1];
    int sum = k0 + k1;
    int xp = sum;
#pragma unroll
    for (int d = 1; d < 64; d <<= 1) {
        int y = __shfl_up(xp, d, 64);
        if (lane >= d) xp += y;
    }
    if (lane == 63) scanA[w] = xp;
    __syncthreads();
    if (w == 0) {
        int v = (lane < 16) ? scanA[lane] : 0;
#pragma unroll
        for (int d = 1; d < 16; d <<= 1) {
            int y = __shfl_up(v, d, 64);
            if (lane >= d) v += y;
        }
        if (lane < 16) scanA[lane] = v;
    }
    __syncthreads();
    int pre = xp + ((w > 0) ? scanA[w - 1] : 0);
    int ex = pre - sum;
    if (k0 && ex < KMAX) sel[ex] = j0;
    if (k1 && (ex + k0) < KMAX) sel[ex + k0] = j1;
    __syncthreads();

    if (t < KMAX) {
        int jj = sel[t];
        float xo = 0.f, yo = 0.f, so = 0.f;
        if (jj >= 0) {
            uint32_t idx = ~(uint32_t)keys2[jj];
            xo = (float)(idx & (Wn - 1));
            yo = (float)(idx >> 10);
            so = __uint_as_float((uint32_t)(keys2[jj] >> 32));
        }
        kp_out[(size_t)b * KMAX * 2 + 2 * t]     = xo;
        kp_out[(size_t)b * KMAX * 2 + 2 * t + 1] = yo;
        sc_out[(size_t)b * KMAX + t]             = so;
    }
}

extern "C" void kernel_launch(void* const* d_in, const int* in_sizes, int n_in,
                              void* d_out, int out_size, void* d_ws, size_t ws_size,
                              hipStream_t stream) {
    const float* gray = (const float*)d_in[0];
    const float* mask = (const float*)d_in[1];
    float* out = (float*)d_out;
    float* kp_out = out;                        // 16*512*2
    float* sc_out = out + (size_t)Bn * KMAX * 2;

    uint64_t* slots = (uint64_t*)d_ws;          // 16*72*256*8 = 2.36 MB, fully rewritten

    dim3 g1(XS, 4, Bn);                         // (18, 4, 16) = 1152 blocks
    detect_kernel<<<g1, 256, 0, stream>>>(gray, mask, slots);
    topk_nms_kernel<<<Bn, 1024, 0, stream>>>(slots, kp_out, sc_out);
}